// Round 6
// baseline (294.569 us; speedup 1.0000x reference)
//
#include <hip/hip_runtime.h>
#include <stdint.h>

typedef __attribute__((ext_vector_type(8))) __bf16 bf16x8;
typedef __attribute__((ext_vector_type(16))) float f32x16;

__device__ inline unsigned short f32_to_bf16_rne(float f) {
  union { float f; uint32_t u; } c; c.f = f;
  uint32_t u = c.u;
  uint32_t r = (u + 0x7FFFu + ((u >> 16) & 1u)) >> 16;
  return (unsigned short)r;
}

// ---------- pass 1: x (f32) -> A (bf16 bits) ----------
__global__ __launch_bounds__(256) void convert_x_kernel(const float* __restrict__ X,
                                                        unsigned short* __restrict__ A,
                                                        size_t n) {
  size_t i = (size_t)blockIdx.x * 256 + threadIdx.x;
  size_t stride = (size_t)gridDim.x * 256;
  for (size_t e = i * 4; e < n; e += stride * 4) {
    const float4 v = *reinterpret_cast<const float4*>(X + e);
    ushort4 o;
    o.x = f32_to_bf16_rne(v.x);
    o.y = f32_to_bf16_rne(v.y);
    o.z = f32_to_bf16_rne(v.z);
    o.w = f32_to_bf16_rne(v.w);
    *reinterpret_cast<ushort4*>(A + e) = o;
  }
}

// ---------- pass 2: Bt[n][k] = sign(Km[k][n]) as bf16 (+1/-1 exact) ----------
__global__ __launch_bounds__(256) void sign_transpose_kernel(const float* __restrict__ Km,
                                                             unsigned short* __restrict__ Bt,
                                                             int K, int N) {
  __shared__ unsigned short tile[64][65];
  const int k0 = blockIdx.x * 64;
  const int n0 = blockIdx.y * 64;
  const int t = threadIdx.x;
#pragma unroll
  for (int i = 0; i < 16; ++i) {
    int idx = t + i * 256;
    int kk = idx >> 6, nn = idx & 63;
    float v = Km[(size_t)(k0 + kk) * N + (n0 + nn)];
    tile[kk][nn] = (v >= 0.0f) ? (unsigned short)0x3F80u : (unsigned short)0xBF80u;
  }
  __syncthreads();
#pragma unroll
  for (int i = 0; i < 16; ++i) {
    int idx = t + i * 256;
    int nn = idx >> 6, kk = idx & 63;
    Bt[(size_t)(n0 + nn) * K + (k0 + kk)] = tile[kk][nn];
  }
}

// ---------- pass 3: 256x256-tile bf16 MFMA GEMM, 32x32x16 shape ----------
// A: [M][K] bf16 row-major; Bt: [N][K] bf16 row-major; C: [M][N] f32.
// 512 threads = 8 waves in 2(M)x4(N); wave output 128x64 as 4x2 tiles of
// 32x32, mfma_f32_32x32x16_bf16. BK=32 K-tiles, 4-deep circular LDS buffer.
//
// Pipeline skeleton identical to r4 (proven race-free, ran r2-r4):
//  - cluster-0 operands (AFC rows 0-63, BFC) preloaded previous iter
//  - af1 (rows 64-127) + 2 of 4 next-B reads overlap cluster 0
//  - remaining next-B + next-A reads overlap cluster 1
//  - one s_waitcnt vmcnt(4) + one s_barrier per iter
// INVARIANT entering iter t: tiles <= t+1 landed from all waves. Iter t
// reads tile t (af1) and tile t+1 (prefetch). Staging target
// buf[(t+3)&3]=buf[(t-1)&3] fully consumed before barrier t-1.
//
// SLOT ADDRESSING (r5 bug fixed): row = 64 B = 4 slots of 16 B. Logical
// slot for a frag read = 2*ks + hi (hi = lane>>5, ks = k-half). Stage wrote
// physical slot p <- logical p ^ swz, swz = (row>>1)&3. Read must use
// physical = (2*ks+hi) ^ swz. Since 2*ks toggles only bit 1:
// (2*ks+hi)^swz = ((hi^swz)) ^ (ks<<1)  => byte-index XOR (ks<<4) shorts.
// r5 ERRONEOUSLY ADDED ks*16 after the XOR, overflowing the row for half
// the rows (swz bit1 set). All other index terms have bit 4 clear, so
// applying ^(ks<<4) to the final short-index is exact.
// Bank check (fixed pattern, per 16-lane group): banks touched =
// 16*(r&1) + phys_slot*4 + 0..3 -> each bank exactly 2 lanes = free (m136).
// C/D (verified m74/m101): col=lane&31, row=(reg&3)+8*(reg>>2)+4*(lane>>5).

__device__ __forceinline__ void stage_mat(const unsigned short* __restrict__ G,
                                          size_t grow0, int K, int k0,
                                          unsigned short* lds_wave_base,  // wave-uniform
                                          int tid) {
#pragma unroll
  for (int i = 0; i < 2; ++i) {
    const int row = i * 128 + (tid >> 2);                 // 0..255
    const int srcslot = (tid & 3) ^ ((row >> 1) & 3);     // pre-swizzled source
    const unsigned short* ga = G + (grow0 + row) * (size_t)K + k0 + srcslot * 8;
    __builtin_amdgcn_global_load_lds(
        (const __attribute__((address_space(1))) void*)ga,
        (__attribute__((address_space(3))) void*)(lds_wave_base + i * 4096),
        16, 0, 0);
  }
}

// One pipelined iteration. AFC/BFC: current operands in regs (A rows 0-63 +
// all B). AFN/BFN get next iteration's operands.
// Frag index convention: [2*blk + ks]; read addr = (base + blk*1024) ^ (ks<<4).
#define GEMM_ITER(T, AFC, BFC, AFN, BFN)                                              \
  {                                                                                   \
    const int cb = ((T) & 3) * 16384;                                                 \
    const int ts = ((T) + 3 < NTt) ? ((T) + 3) : (NTt - 1);                           \
    const int tb = (ts & 3) * 16384;                                                  \
    const int nb = ((T) + 1 < NTt) ? ((((T) + 1) & 3) * 16384) : cb;                  \
    bf16x8 af1[4];                                                                    \
    _Pragma("unroll")                                                                 \
    for (int j = 0; j < 4; ++j)                                                       \
      af1[j] = *reinterpret_cast<const bf16x8*>(                                      \
          &lds[(cb + aoff + (2 + (j >> 1)) * 1024) ^ ((j & 1) << 4)]);                \
    _Pragma("unroll")                                                                 \
    for (int j = 0; j < 2; ++j)                                                       \
      BFN[j] = *reinterpret_cast<const bf16x8*>(&lds[(nb + boff) ^ ((j & 1) << 4)]);  \
    stage_mat(A, a_row0, K, ts * 32, &lds[tb + wv * 512], tid);                       \
    __builtin_amdgcn_sched_barrier(0);                                                \
    __builtin_amdgcn_s_setprio(1);                                                    \
    _Pragma("unroll")                                                                 \
    for (int ks = 0; ks < 2; ++ks)                                                    \
      _Pragma("unroll")                                                               \
      for (int rb = 0; rb < 2; ++rb)                                                  \
        _Pragma("unroll")                                                             \
        for (int cbn = 0; cbn < 2; ++cbn)                                             \
          acc[rb][cbn] = __builtin_amdgcn_mfma_f32_32x32x16_bf16(                     \
              AFC[2 * rb + ks], BFC[2 * cbn + ks], acc[rb][cbn], 0, 0, 0);            \
    __builtin_amdgcn_s_setprio(0);                                                    \
    __builtin_amdgcn_sched_barrier(0);                                                \
    _Pragma("unroll")                                                                 \
    for (int j = 2; j < 4; ++j)                                                       \
      BFN[j] = *reinterpret_cast<const bf16x8*>(                                      \
          &lds[(nb + boff + 1024) ^ ((j & 1) << 4)]);                                 \
    _Pragma("unroll")                                                                 \
    for (int j = 0; j < 4; ++j)                                                       \
      AFN[j] = *reinterpret_cast<const bf16x8*>(                                      \
          &lds[(nb + aoff + (j >> 1) * 1024) ^ ((j & 1) << 4)]);                      \
    stage_mat(Bt, b_row0, K, ts * 32, &lds[tb + 8192 + wv * 512], tid);               \
    __builtin_amdgcn_sched_barrier(0);                                                \
    __builtin_amdgcn_s_setprio(1);                                                    \
    _Pragma("unroll")                                                                 \
    for (int ks = 0; ks < 2; ++ks)                                                    \
      _Pragma("unroll")                                                               \
      for (int rb = 0; rb < 2; ++rb)                                                  \
        _Pragma("unroll")                                                             \
        for (int cbn = 0; cbn < 2; ++cbn)                                             \
          acc[2 + rb][cbn] = __builtin_amdgcn_mfma_f32_32x32x16_bf16(                 \
              af1[2 * rb + ks], BFC[2 * cbn + ks], acc[2 + rb][cbn], 0, 0, 0);        \
    __builtin_amdgcn_s_setprio(0);                                                    \
    asm volatile("s_waitcnt vmcnt(4)\n" ::: "memory");                                \
    __builtin_amdgcn_s_barrier();                                                     \
  }

__global__ __launch_bounds__(512, 2) void gemm_bf16_256(const unsigned short* __restrict__ A,
                                                        const unsigned short* __restrict__ Bt,
                                                        float* __restrict__ C,
                                                        int M, int N, int K) {
  __shared__ unsigned short lds[4 * 16384];  // 128 KiB; per buf: A[256][32] then B[256][32]

  const int nBN = N >> 8;
  const int nwg = gridDim.x;
  const int bid = blockIdx.x;
  int swz = bid;
  if ((nwg & 7) == 0) {  // bijective XCD swizzle
    const int q = nwg >> 3;
    swz = (bid & 7) * q + (bid >> 3);
  }
  const size_t a_row0 = (size_t)(swz / nBN) * 256;
  const size_t b_row0 = (size_t)(swz % nBN) * 256;

  const int tid = threadIdx.x;
  const int wv = tid >> 6, ln = tid & 63;
  const int r5 = ln & 31, hi = ln >> 5;
  const int wr = wv >> 2, wc = wv & 3;

  // per-lane ds_read bases (shorts): ks=0 physical slot = (hi ^ swz(row));
  // ks=1 address = ks=0 address XOR 16 shorts (see header comment).
  const int slot0 = (hi ^ ((r5 >> 1) & 3)) * 8;
  const int aoff = (wr * 128 + r5) * 32 + slot0;         // + blk*1024, ^ (ks<<4)
  const int boff = 8192 + (wc * 64 + r5) * 32 + slot0;   // + blk*1024, ^ (ks<<4)

  const int NTt = K >> 5;  // 128 K-tiles (even; launch guards K%128==0)

  f32x16 acc[4][2];
#pragma unroll
  for (int i = 0; i < 4; ++i)
#pragma unroll
    for (int j = 0; j < 2; ++j)
#pragma unroll
      for (int r = 0; r < 16; ++r) acc[i][j][r] = 0.f;

  // ---- prologue: stage tiles 0,1,2; confirm tiles 0 AND 1; preload t=0 ----
#pragma unroll
  for (int tt = 0; tt < 3; ++tt) {
    stage_mat(A, a_row0, K, tt * 32, &lds[tt * 16384 + wv * 512], tid);
    stage_mat(Bt, b_row0, K, tt * 32, &lds[tt * 16384 + 8192 + wv * 512], tid);
  }
  asm volatile("s_waitcnt vmcnt(4)\n" ::: "memory");
  __builtin_amdgcn_s_barrier();

  bf16x8 af0_a[4], bfr_a[4], af0_b[4], bfr_b[4];
#pragma unroll
  for (int j = 0; j < 4; ++j)
    bfr_a[j] = *reinterpret_cast<const bf16x8*>(&lds[(boff + (j >> 1) * 1024) ^ ((j & 1) << 4)]);
#pragma unroll
  for (int j = 0; j < 4; ++j)
    af0_a[j] = *reinterpret_cast<const bf16x8*>(&lds[(aoff + (j >> 1) * 1024) ^ ((j & 1) << 4)]);

  // ---- main loop: 2x unrolled, ping-pong register sets ----
  for (int t = 0; t < NTt; t += 2) {
    GEMM_ITER(t, af0_a, bfr_a, af0_b, bfr_b)
    GEMM_ITER(t + 1, af0_b, bfr_b, af0_a, bfr_a)
  }

  // ---- epilogue: 32x32 C/D: col=lane&31, row=(reg&3)+8*(reg>>2)+4*hi ----
#pragma unroll
  for (int rb = 0; rb < 4; ++rb) {
#pragma unroll
    for (int cbn = 0; cbn < 2; ++cbn) {
      const size_t col = b_row0 + wc * 64 + cbn * 32 + r5;
      const size_t rbase = a_row0 + wr * 128 + rb * 32 + 4 * hi;
#pragma unroll
      for (int r = 0; r < 16; ++r) {
        const size_t row = rbase + (r & 3) + 8 * (r >> 2);
        C[row * (size_t)N + col] = acc[rb][cbn][r];
      }
    }
  }
}

// ---------- fallback: f32 tiled GEMM (only if ws_size too small) ----------
__global__ __launch_bounds__(256) void gemm_f32_fallback(const float* __restrict__ X,
                                                         const float* __restrict__ Km,
                                                         float* __restrict__ C,
                                                         int M, int N, int K) {
  __shared__ float As[64][16];
  __shared__ float Bs[16][65];
  const int nBN = N / 64;
  const int bm = blockIdx.x / nBN;
  const int bn = blockIdx.x % nBN;
  const int t = threadIdx.x;
  const int tx = t & 15, ty = t >> 4;
  float acc[4][4] = {};
  for (int kb = 0; kb < K; kb += 16) {
#pragma unroll
    for (int i = 0; i < 4; ++i) {
      int e = t + i * 256;
      int r = e >> 4, c = e & 15;
      As[r][c] = X[(size_t)(bm * 64 + r) * K + kb + c];
      int rk = e >> 6, cn = e & 63;
      float v = Km[(size_t)(kb + rk) * N + bn * 64 + cn];
      Bs[rk][cn] = (v >= 0.f) ? 1.f : -1.f;
    }
    __syncthreads();
#pragma unroll
    for (int kk = 0; kk < 16; ++kk) {
      float a[4], b[4];
#pragma unroll
      for (int r = 0; r < 4; ++r) a[r] = As[ty * 4 + r][kk];
#pragma unroll
      for (int c = 0; c < 4; ++c) b[c] = Bs[kk][tx * 4 + c];
#pragma unroll
      for (int r = 0; r < 4; ++r)
#pragma unroll
        for (int c = 0; c < 4; ++c) acc[r][c] += a[r] * b[c];
    }
    __syncthreads();
  }
#pragma unroll
  for (int r = 0; r < 4; ++r)
#pragma unroll
    for (int c = 0; c < 4; ++c)
      C[(size_t)(bm * 64 + ty * 4 + r) * N + bn * 64 + tx * 4 + c] = acc[r][c];
}

extern "C" void kernel_launch(void* const* d_in, const int* in_sizes, int n_in,
                              void* d_out, int out_size, void* d_ws, size_t ws_size,
                              hipStream_t stream) {
  const float* x = (const float*)d_in[0];
  const float* kern = (const float*)d_in[1];
  float* out = (float*)d_out;

  const int K = 4096;             // D_IN
  const int N = 4096;             // UNITS
  const int M = in_sizes[0] / K;  // 8192

  const size_t a_bytes = (size_t)M * K * 2;
  const size_t b_bytes = (size_t)N * K * 2;

  if (ws_size >= a_bytes + b_bytes && (M % 256) == 0 && (N % 256) == 0 && (K % 128) == 0) {
    unsigned short* A = (unsigned short*)d_ws;
    unsigned short* Bt = (unsigned short*)((char*)d_ws + a_bytes);
    convert_x_kernel<<<2048, 256, 0, stream>>>(x, A, (size_t)M * K);
    sign_transpose_kernel<<<dim3(K / 64, N / 64), 256, 0, stream>>>(kern, Bt, K, N);
    gemm_bf16_256<<<(M / 256) * (N / 256), 512, 0, stream>>>(A, Bt, out, M, N, K);
  } else {
    gemm_f32_fallback<<<(M / 64) * (N / 64), 256, 0, stream>>>(x, kern, out, M, N, K);
  }
}

// Round 7
// 272.635 us; speedup vs baseline: 1.0805x; 1.0805x over previous
//
#include <hip/hip_runtime.h>
#include <stdint.h>

typedef __attribute__((ext_vector_type(8))) __bf16 bf16x8;
typedef __attribute__((ext_vector_type(4))) float f32x4;

__device__ inline unsigned short f32_to_bf16_rne(float f) {
  union { float f; uint32_t u; } c; c.f = f;
  uint32_t u = c.u;
  uint32_t r = (u + 0x7FFFu + ((u >> 16) & 1u)) >> 16;
  return (unsigned short)r;
}

// ---------- pass 1: x (f32) -> A (bf16 bits) ----------
__global__ __launch_bounds__(256) void convert_x_kernel(const float* __restrict__ X,
                                                        unsigned short* __restrict__ A,
                                                        size_t n) {
  size_t i = (size_t)blockIdx.x * 256 + threadIdx.x;
  size_t stride = (size_t)gridDim.x * 256;
  for (size_t e = i * 4; e < n; e += stride * 4) {
    const float4 v = *reinterpret_cast<const float4*>(X + e);
    ushort4 o;
    o.x = f32_to_bf16_rne(v.x);
    o.y = f32_to_bf16_rne(v.y);
    o.z = f32_to_bf16_rne(v.z);
    o.w = f32_to_bf16_rne(v.w);
    *reinterpret_cast<ushort4*>(A + e) = o;
  }
}

// ---------- pass 2: Bt[n][k] = sign(Km[k][n]) as bf16 (+1/-1 exact) ----------
__global__ __launch_bounds__(256) void sign_transpose_kernel(const float* __restrict__ Km,
                                                             unsigned short* __restrict__ Bt,
                                                             int K, int N) {
  __shared__ unsigned short tile[64][65];
  const int k0 = blockIdx.x * 64;
  const int n0 = blockIdx.y * 64;
  const int t = threadIdx.x;
#pragma unroll
  for (int i = 0; i < 16; ++i) {
    int idx = t + i * 256;
    int kk = idx >> 6, nn = idx & 63;
    float v = Km[(size_t)(k0 + kk) * N + (n0 + nn)];
    tile[kk][nn] = (v >= 0.0f) ? (unsigned short)0x3F80u : (unsigned short)0xBF80u;
  }
  __syncthreads();
#pragma unroll
  for (int i = 0; i < 16; ++i) {
    int idx = t + i * 256;
    int nn = idx >> 6, kk = idx & 63;
    Bt[(size_t)(n0 + nn) * K + (k0 + kk)] = tile[kk][nn];
  }
}

// ---------- pass 3: 256x256-tile bf16 MFMA GEMM, reg-double-buffered ----------
// EXACT r4 kernel (16x16x32 shape, 0 bank conflicts, proven) with ONE change:
// the read windows are rebalanced 6/6 instead of 4/8. Phase 0 now carries
// af1[0..3] + BFN[0..1]; phase 1 carries BFN[2..3] + AFN[0..3]. Reading tile
// t+1 (nb) in phase 0 is legal: the entry invariant guarantees tiles <= t+1
// are landed from all waves (vmcnt(4) at end of iter t-1 with stages issued
// through tile t+2). 32x32x16 shape REVERTED (r6: it re-introduced 2.5e7
// bank conflicts on the same swizzle; mechanism unmodeled -> not used).
//
// Pipeline safety (unchanged from r4, ran r2-r4 + r6 without races):
//  - one s_waitcnt vmcnt(4) + one s_barrier per iter
//  - staging target buf[(t+3)&3]=buf[(t-1)&3] fully consumed before B(t-1)
//  - tail: ts clamps to NT-1 (re-stage identical bytes); nb clamps to cb
// T2 swizzle: row = 64 B = 4 slots of 16 B; slot ^= (row>>1)&3 (2-way free).
// gl_lds dest linear; GLOBAL source k-chunk pre-swizzled (rule 21).

__device__ __forceinline__ void stage_mat(const unsigned short* __restrict__ G,
                                          size_t grow0, int K, int k0,
                                          unsigned short* lds_wave_base,  // wave-uniform
                                          int tid) {
#pragma unroll
  for (int i = 0; i < 2; ++i) {
    const int row = i * 128 + (tid >> 2);                 // 0..255
    const int srcslot = (tid & 3) ^ ((row >> 1) & 3);     // pre-swizzled source
    const unsigned short* ga = G + (grow0 + row) * (size_t)K + k0 + srcslot * 8;
    __builtin_amdgcn_global_load_lds(
        (const __attribute__((address_space(1))) void*)ga,
        (__attribute__((address_space(3))) void*)(lds_wave_base + i * 4096),
        16, 0, 0);
  }
}

// One pipelined iteration. AFC/BFC: current cluster-0 operands (already in
// regs). AFN/BFN: written with next iteration's cluster-0 operands.
#define GEMM_ITER(T, AFC, BFC, AFN, BFN)                                              \
  {                                                                                   \
    const int cb = ((T) & 3) * 16384;                                                 \
    const int ts = ((T) + 3 < NTt) ? ((T) + 3) : (NTt - 1);                           \
    const int tb = (ts & 3) * 16384;                                                  \
    const int nb = ((T) + 1 < NTt) ? ((((T) + 1) & 3) * 16384) : cb;                  \
    bf16x8 af1[4];                                                                    \
    _Pragma("unroll")                                                                 \
    for (int mi = 0; mi < 4; ++mi)                                                    \
      af1[mi] = *reinterpret_cast<const bf16x8*>(&lds[cb + aoff + 2048 + mi * 512]);  \
    _Pragma("unroll")                                                                 \
    for (int ni = 0; ni < 2; ++ni)                                                    \
      BFN[ni] = *reinterpret_cast<const bf16x8*>(&lds[nb + boff + ni * 512]);         \
    stage_mat(A, a_row0, K, ts * 32, &lds[tb + wv * 512], tid);                       \
    __builtin_amdgcn_sched_barrier(0);                                                \
    __builtin_amdgcn_s_setprio(1);                                                    \
    _Pragma("unroll")                                                                 \
    for (int mi = 0; mi < 4; ++mi)                                                    \
      _Pragma("unroll")                                                               \
      for (int ni = 0; ni < 4; ++ni)                                                  \
        acc[mi][ni] =                                                                 \
            __builtin_amdgcn_mfma_f32_16x16x32_bf16(AFC[mi], BFC[ni], acc[mi][ni], 0, 0, 0); \
    __builtin_amdgcn_s_setprio(0);                                                    \
    __builtin_amdgcn_sched_barrier(0);                                                \
    _Pragma("unroll")                                                                 \
    for (int ni = 2; ni < 4; ++ni)                                                    \
      BFN[ni] = *reinterpret_cast<const bf16x8*>(&lds[nb + boff + ni * 512]);         \
    _Pragma("unroll")                                                                 \
    for (int mi = 0; mi < 4; ++mi)                                                    \
      AFN[mi] = *reinterpret_cast<const bf16x8*>(&lds[nb + aoff + mi * 512]);         \
    stage_mat(Bt, b_row0, K, ts * 32, &lds[tb + 8192 + wv * 512], tid);               \
    __builtin_amdgcn_sched_barrier(0);                                                \
    __builtin_amdgcn_s_setprio(1);                                                    \
    _Pragma("unroll")                                                                 \
    for (int mi = 0; mi < 4; ++mi)                                                    \
      _Pragma("unroll")                                                               \
      for (int ni = 0; ni < 4; ++ni)                                                  \
        acc[4 + mi][ni] =                                                             \
            __builtin_amdgcn_mfma_f32_16x16x32_bf16(af1[mi], BFC[ni], acc[4 + mi][ni], 0, 0, 0); \
    __builtin_amdgcn_s_setprio(0);                                                    \
    asm volatile("s_waitcnt vmcnt(4)\n" ::: "memory");                                \
    __builtin_amdgcn_s_barrier();                                                     \
  }

__global__ __launch_bounds__(512, 2) void gemm_bf16_256(const unsigned short* __restrict__ A,
                                                        const unsigned short* __restrict__ Bt,
                                                        float* __restrict__ C,
                                                        int M, int N, int K) {
  __shared__ unsigned short lds[4 * 16384];  // 128 KiB; per buf: A[256][32] then B[256][32]

  const int nBN = N >> 8;
  const int nwg = gridDim.x;
  const int bid = blockIdx.x;
  int swz = bid;
  if ((nwg & 7) == 0) {  // bijective XCD swizzle
    const int q = nwg >> 3;
    swz = (bid & 7) * q + (bid >> 3);
  }
  const size_t a_row0 = (size_t)(swz / nBN) * 256;
  const size_t b_row0 = (size_t)(swz % nBN) * 256;

  const int tid = threadIdx.x;
  const int wv = tid >> 6, ln = tid & 63;
  const int llo = ln & 15, lhi = ln >> 4;
  const int wr = wv >> 2, wc = wv & 3;
  const int sA = lhi ^ ((llo >> 1) & 3);  // swizzled 16B-slot for ds_read

  // per-lane ds_read bases (shorts, relative to buf start)
  const int aoff = (wr * 128 + llo) * 32 + sA * 8;
  const int boff = 8192 + (wc * 64 + llo) * 32 + sA * 8;

  const int NTt = K >> 5;  // 128 K-tiles (even; launch guards K%128==0)

  f32x4 acc[8][4];
#pragma unroll
  for (int i = 0; i < 8; ++i)
#pragma unroll
    for (int j = 0; j < 4; ++j) acc[i][j] = (f32x4){0.f, 0.f, 0.f, 0.f};

  // ---- prologue: stage tiles 0,1,2; confirm tiles 0 AND 1; preload t=0 ----
#pragma unroll
  for (int tt = 0; tt < 3; ++tt) {
    stage_mat(A, a_row0, K, tt * 32, &lds[tt * 16384 + wv * 512], tid);
    stage_mat(Bt, b_row0, K, tt * 32, &lds[tt * 16384 + 8192 + wv * 512], tid);
  }
  asm volatile("s_waitcnt vmcnt(4)\n" ::: "memory");
  __builtin_amdgcn_s_barrier();

  bf16x8 af0_a[4], bfr_a[4], af0_b[4], bfr_b[4];
#pragma unroll
  for (int ni = 0; ni < 4; ++ni)
    bfr_a[ni] = *reinterpret_cast<const bf16x8*>(&lds[boff + ni * 512]);
#pragma unroll
  for (int mi = 0; mi < 4; ++mi)
    af0_a[mi] = *reinterpret_cast<const bf16x8*>(&lds[aoff + mi * 512]);

  // ---- main loop: 2x unrolled, ping-pong register sets ----
  for (int t = 0; t < NTt; t += 2) {
    GEMM_ITER(t, af0_a, bfr_a, af0_b, bfr_b)
    GEMM_ITER(t + 1, af0_b, bfr_b, af0_a, bfr_a)
  }

  // ---- epilogue: C/D layout col = lane&15, row = (lane>>4)*4 + reg ----
#pragma unroll
  for (int mi = 0; mi < 8; ++mi) {
#pragma unroll
    for (int ni = 0; ni < 4; ++ni) {
      const size_t col = b_row0 + wc * 64 + ni * 16 + llo;
      const size_t rbase = a_row0 + wr * 128 + mi * 16 + lhi * 4;
#pragma unroll
      for (int j = 0; j < 4; ++j)
        C[(rbase + j) * (size_t)N + col] = acc[mi][ni][j];
    }
  }
}

// ---------- fallback: f32 tiled GEMM (only if ws_size too small) ----------
__global__ __launch_bounds__(256) void gemm_f32_fallback(const float* __restrict__ X,
                                                         const float* __restrict__ Km,
                                                         float* __restrict__ C,
                                                         int M, int N, int K) {
  __shared__ float As[64][16];
  __shared__ float Bs[16][65];
  const int nBN = N / 64;
  const int bm = blockIdx.x / nBN;
  const int bn = blockIdx.x % nBN;
  const int t = threadIdx.x;
  const int tx = t & 15, ty = t >> 4;
  float acc[4][4] = {};
  for (int kb = 0; kb < K; kb += 16) {
#pragma unroll
    for (int i = 0; i < 4; ++i) {
      int e = t + i * 256;
      int r = e >> 4, c = e & 15;
      As[r][c] = X[(size_t)(bm * 64 + r) * K + kb + c];
      int rk = e >> 6, cn = e & 63;
      float v = Km[(size_t)(kb + rk) * N + bn * 64 + cn];
      Bs[rk][cn] = (v >= 0.f) ? 1.f : -1.f;
    }
    __syncthreads();
#pragma unroll
    for (int kk = 0; kk < 16; ++kk) {
      float a[4], b[4];
#pragma unroll
      for (int r = 0; r < 4; ++r) a[r] = As[ty * 4 + r][kk];
#pragma unroll
      for (int c = 0; c < 4; ++c) b[c] = Bs[kk][tx * 4 + c];
#pragma unroll
      for (int r = 0; r < 4; ++r)
#pragma unroll
        for (int c = 0; c < 4; ++c) acc[r][c] += a[r] * b[c];
    }
    __syncthreads();
  }
#pragma unroll
  for (int r = 0; r < 4; ++r)
#pragma unroll
    for (int c = 0; c < 4; ++c)
      C[(size_t)(bm * 64 + ty * 4 + r) * N + bn * 64 + tx * 4 + c] = acc[r][c];
}

extern "C" void kernel_launch(void* const* d_in, const int* in_sizes, int n_in,
                              void* d_out, int out_size, void* d_ws, size_t ws_size,
                              hipStream_t stream) {
  const float* x = (const float*)d_in[0];
  const float* kern = (const float*)d_in[1];
  float* out = (float*)d_out;

  const int K = 4096;             // D_IN
  const int N = 4096;             // UNITS
  const int M = in_sizes[0] / K;  // 8192

  const size_t a_bytes = (size_t)M * K * 2;
  const size_t b_bytes = (size_t)N * K * 2;

  if (ws_size >= a_bytes + b_bytes && (M % 256) == 0 && (N % 256) == 0 && (K % 128) == 0) {
    unsigned short* A = (unsigned short*)d_ws;
    unsigned short* Bt = (unsigned short*)((char*)d_ws + a_bytes);
    convert_x_kernel<<<2048, 256, 0, stream>>>(x, A, (size_t)M * K);
    sign_transpose_kernel<<<dim3(K / 64, N / 64), 256, 0, stream>>>(kern, Bt, K, N);
    gemm_bf16_256<<<(M / 256) * (N / 256), 512, 0, stream>>>(A, Bt, out, M, N, K);
  } else {
    gemm_f32_fallback<<<(M / 64) * (N / 64), 256, 0, stream>>>(x, kern, out, M, N, K);
  }
}